// Round 3
// baseline (140.328 us; speedup 1.0000x reference)
//
#include <hip/hip_runtime.h>
#include <hip/hip_bf16.h>
#include <hip/hip_fp16.h>

// Tables: ESP/EIP = exp(-proj logit) in FP16; ECS/ECI = exp(-conc logit) in
// FP8 e4m3 (R5: concept rows are 512MB of the 640MB edge gather traffic and
// are L2-resident — halving their bytes attacks the measured memory bound;
// e4m3 rel err ~3.6% rms -> output err ~+4e-3, threshold 1.96e-2).
// Edge: sigma(a)-sigma(b) = (u-t)/((1+t)(1+u)), t=ESP*ECS, u=EIP*ECI, packed
// fp16 front-end; 2-level fraction pair-tree in F32 (v_fma_mix) -> 2 rcps
// per lane*k (R4). Denominators pre-scaled 0.25, w_pred pre-scaled 0.25
// (scales cancel exactly in N2/D2). DPP butterfly reduction — no LDS.
// Timed-region model (R2 counters): 2x 256MiB harness poison fills ~89us are
// structural; controllable = proj ~4us + edge ~40us (memory-bound).
constexpr int EDGES = 250000;
constexpr int EMB   = 64;
constexpr int CNUM  = 128;
constexpr int NSTU  = 10000;
constexpr int NITEM = 50000;
constexpr int NCONC = 2048;

constexpr float NEG_LOG2E = -1.44269504088896340736f;

// proj job space: one wave per 16-row strip (conc strips: one wave per table)
constexpr int STU_JOBS  = NSTU  / 16;            // 625
constexpr int ITEM_JOBS = NITEM / 16;            // 3125
constexpr int CONC_JOBS = (NCONC / 16) * 2;      // 256
constexpr int NJOBS     = STU_JOBS + ITEM_JOBS + CONC_JOBS;  // 4006
constexpr int PROJ_BLKS = (NJOBS + 3) / 4;

typedef _Float16 h8 __attribute__((ext_vector_type(8)));
typedef _Float16 h4 __attribute__((ext_vector_type(4)));
typedef _Float16 h2 __attribute__((ext_vector_type(2)));
typedef float    f32x4 __attribute__((ext_vector_type(4)));
typedef float    f32x2 __attribute__((ext_vector_type(2)));

__device__ __forceinline__ h2 cvt2(float a, float b) {
#if __has_builtin(__builtin_amdgcn_cvt_pkrtz)
    return __builtin_bit_cast(h2, __builtin_amdgcn_cvt_pkrtz(a, b));
#else
    h2 r; r[0] = (_Float16)a; r[1] = (_Float16)b; return r;
#endif
}

__device__ __forceinline__ h8 pack8(float4 lo, float4 hi) {
    const h2 a = cvt2(lo.x, lo.y);
    const h2 b = cvt2(lo.z, lo.w);
    const h2 c = cvt2(hi.x, hi.y);
    const h2 d = cvt2(hi.z, hi.w);
    const h4 ab = __builtin_shufflevector(a, b, 0, 1, 2, 3);
    const h4 cd = __builtin_shufflevector(c, d, 0, 1, 2, 3);
    return __builtin_shufflevector(ab, cd, 0, 1, 2, 3, 4, 5, 6, 7);
}

// decode 8 fp8 e4m3 bytes -> h8 (4x v_cvt_pk_f32_fp8 + 4x v_cvt_pkrtz)
__device__ __forceinline__ h8 dec8(uint2 v) {
    const f32x2 a = __builtin_amdgcn_cvt_pk_f32_fp8(v.x, false);
    const f32x2 b = __builtin_amdgcn_cvt_pk_f32_fp8(v.x, true);
    const f32x2 c = __builtin_amdgcn_cvt_pk_f32_fp8(v.y, false);
    const f32x2 d = __builtin_amdgcn_cvt_pk_f32_fp8(v.y, true);
    const h2 h0 = cvt2(a[0], a[1]);
    const h2 h1 = cvt2(b[0], b[1]);
    const h2 h2v = cvt2(c[0], c[1]);
    const h2 h3 = cvt2(d[0], d[1]);
    const h4 lo = __builtin_shufflevector(h0, h1, 0, 1, 2, 3);
    const h4 hi = __builtin_shufflevector(h2v, h3, 0, 1, 2, 3);
    return __builtin_shufflevector(lo, hi, 0, 1, 2, 3, 4, 5, 6, 7);
}

// x += dpp-permuted x (full-rate VALU, no LDS pipe)
template <int CTRL>
__device__ __forceinline__ float dppadd(float x) {
    return x + __int_as_float(__builtin_amdgcn_update_dpp(
        0, __float_as_int(x), CTRL, 0xf, 0xf, true));
}

// ---- projection via MFMA: O[r,c] = exp(-dot(F[r,:], W[c, wcol:wcol+64])) ---
__global__ __launch_bounds__(256) void proj_mfma(
        const float* __restrict__ stuF, const float* __restrict__ itemF,
        const float* __restrict__ concF,
        const float* __restrict__ W_stu, const float* __restrict__ W_item,
        const float* __restrict__ w_pred,
        _Float16* __restrict__ ESP, _Float16* __restrict__ EIP,
        unsigned char* __restrict__ ECS8, unsigned char* __restrict__ ECI8,
        _Float16* __restrict__ WH) {
    const int tid  = threadIdx.x;
    const int lane = tid & 63;
    const int job  = blockIdx.x * 4 + (tid >> 6);
    if (job >= NJOBS) return;

    if (job == 0) {  // one wave converts w_pred (128 f32) to fp16, * 0.25
        const float2 wv2 = ((const float2*)w_pred)[lane];
        h2 wh; wh[0] = (_Float16)(wv2.x * 0.25f);
        wh[1] = (_Float16)(wv2.y * 0.25f);
        *(h2*)(WH + 2 * lane) = wh;
    }

    const float* F; const float* W;
    _Float16* O16 = nullptr; unsigned char* O8 = nullptr;
    int strip, wcol; bool is8;
    if (job < STU_JOBS) {
        F = stuF;  W = W_stu;  O16 = ESP; strip = job; wcol = 0; is8 = false;
    } else if (job < STU_JOBS + ITEM_JOBS) {
        F = itemF; W = W_item; O16 = EIP; strip = job - STU_JOBS; wcol = 0;
        is8 = false;
    } else {
        const int g = job - STU_JOBS - ITEM_JOBS;
        F = concF; W = (g & 1) ? W_item : W_stu;
        O8 = (g & 1) ? ECI8 : ECS8;
        strip = g >> 1; wcol = EMB; is8 = true;
    }

    const int m = lane & 15;       // A row / B channel / D col
    const int q = lane >> 4;       // quad
    const int row = strip * 16 + m;

    const float4* fa = (const float4*)(F + (size_t)row * EMB + q * 8);
    const float4* fb = (const float4*)(F + (size_t)row * EMB + 32 + q * 8);
    const h8 A0 = pack8(fa[0], fa[1]);
    const h8 A1 = pack8(fb[0], fb[1]);

    const int orow = strip * 16 + q * 4;

#pragma unroll
    for (int ct = 0; ct < 8; ++ct) {
        const int ch = ct * 16 + m;
        const float* wr = W + (size_t)ch * (2 * EMB) + wcol;
        const float4* wb0 = (const float4*)(wr + q * 8);
        const float4* wb1 = (const float4*)(wr + 32 + q * 8);
        const h8 B0 = pack8(wb0[0], wb0[1]);
        const h8 B1 = pack8(wb1[0], wb1[1]);

        f32x4 acc = {0.f, 0.f, 0.f, 0.f};
        acc = __builtin_amdgcn_mfma_f32_16x16x32_f16(A0, B0, acc, 0, 0, 0);
        acc = __builtin_amdgcn_mfma_f32_16x16x32_f16(A1, B1, acc, 0, 0, 0);

#pragma unroll
        for (int r = 0; r < 4; ++r) {
            const float e = __builtin_amdgcn_exp2f(acc[r] * NEG_LOG2E);
            if (!is8) {
                O16[(size_t)(orow + r) * CNUM + ct * 16 + m] = (_Float16)e;
            } else {
                const int pk = __builtin_amdgcn_cvt_pk_fp8_f32(e, e, 0, false);
                O8[(size_t)(orow + r) * CNUM + ct * 16 + m] =
                    (unsigned char)(pk & 0xff);
            }
        }
    }
}

__device__ __forceinline__ float sigm(float x) {
    return __builtin_amdgcn_rcpf(1.f + __builtin_amdgcn_exp2f(x * NEG_LOG2E));
}

// ---- edge phase: 4 edges/wave, 16 lanes/edge, lane owns 8 channels --------
__global__ __launch_bounds__(256) void edge_kernel(
        const int*  __restrict__ stu_idx,
        const int*  __restrict__ item_idx,
        const int4* __restrict__ conc_idx,
        const _Float16* __restrict__ ESP,
        const _Float16* __restrict__ EIP,
        const unsigned char* __restrict__ ECS8,
        const unsigned char* __restrict__ ECI8,
        const _Float16* __restrict__ WH,
        const float* __restrict__ b_pred,
        float* __restrict__ out) {
    const int lane = threadIdx.x & 63;
    const int wvg  = (blockIdx.x * blockDim.x + threadIdx.x) >> 6;
    const int sub  = lane >> 4;      // edge within wave 0..3
    const int li   = lane & 15;      // lane within edge; owns ch li*8..li*8+7
    const int e    = wvg * 4 + sub;  // grid sized exactly

    const int s  = stu_idx[e];
    const int it = item_idx[e];
    const int4 c4 = conc_idx[e];

    const h8 es = *(const h8*)(ESP + (size_t)s  * CNUM + li * 8);
    const h8 ei = *(const h8*)(EIP + (size_t)it * CNUM + li * 8);
    const h8 w8 = *(const h8*)(WH + li * 8);   // w_pred * 0.25 (pre-scaled)
    const float b = b_pred[0];

    const _Float16 O1 = (_Float16)1.f, QT = (_Float16)0.25f;
    const h8 ONE = {O1, O1, O1, O1, O1, O1, O1, O1};
    const h8 QV  = {QT, QT, QT, QT, QT, QT, QT, QT};

    const int ck[4] = {c4.x, c4.y, c4.z, c4.w};
    float p[4];
#pragma unroll
    for (int k = 0; k < 4; ++k) {
        const uint2 vs = *(const uint2*)(ECS8 + (size_t)ck[k] * CNUM + li * 8);
        const uint2 vi = *(const uint2*)(ECI8 + (size_t)ck[k] * CNUM + li * 8);
        const h8 cs = dec8(vs);
        const h8 ci = dec8(vi);
        const h8 t  = es * cs;               // e^-(sp+cs)   (v_pk_mul)
        const h8 u  = ei * ci;               // e^-(ip+ci)
        const h8 dq = t * QV + QV;           // 0.25*(1+t)   (v_pk_fma)
        const h8 du = u + ONE;               // (1+u)
        const h8 dn = dq * du;               // 0.25*den in [0.25, ~2.5e3]
        const h8 nm = w8 * (u - t);          // (0.25w)(u-t); scales cancel
        // pair-tree in F32 (v_fma_mix reads fp16 ops directly): 8 -> 4 -> 2
        float N1[4], D1[4];
#pragma unroll
        for (int i = 0; i < 4; ++i) {
            N1[i] = (float)nm[i] * (float)dn[i + 4]
                  + (float)nm[i + 4] * (float)dn[i];
            D1[i] = (float)dn[i] * (float)dn[i + 4];
        }
        const float N2a = N1[0] * D1[2] + N1[2] * D1[0];
        const float N2b = N1[1] * D1[3] + N1[3] * D1[1];
        const float D2a = D1[0] * D1[2];
        const float D2b = D1[1] * D1[3];
        // only 2 rcps per (lane,k) instead of 8
        p[k] = N2a * __builtin_amdgcn_rcpf(D2a)
             + N2b * __builtin_amdgcn_rcpf(D2b);
    }

    // 16-lane sum via DPP butterfly; xor-basis {1,2,7,15} spans the group.
#pragma unroll
    for (int j = 0; j < 4; ++j) p[j] = dppadd<0xB1>(p[j]);   // quad_perm xor1
#pragma unroll
    for (int j = 0; j < 4; ++j) p[j] = dppadd<0x4E>(p[j]);   // quad_perm xor2
#pragma unroll
    for (int j = 0; j < 4; ++j) p[j] = dppadd<0x141>(p[j]);  // row_half_mirror
#pragma unroll
    for (int j = 0; j < 4; ++j) p[j] = dppadd<0x140>(p[j]);  // row_mirror

    const float r = 0.25f * (sigm(p[0] + b) + sigm(p[1] + b) +
                             sigm(p[2] + b) + sigm(p[3] + b));
    if (li == 0) out[e] = r;
}

extern "C" void kernel_launch(void* const* d_in, const int* in_sizes, int n_in,
                              void* d_out, int out_size, void* d_ws, size_t ws_size,
                              hipStream_t stream) {
    const int* stu_idx  = (const int*)d_in[0];
    const int* item_idx = (const int*)d_in[1];
    const int* conc_idx = (const int*)d_in[2];
    const float* stu_fusion     = (const float*)d_in[3];
    const float* item_fusion    = (const float*)d_in[4];
    const float* concept_fusion = (const float*)d_in[5];
    const float* W_stu          = (const float*)d_in[6];
    const float* W_item         = (const float*)d_in[7];
    const float* w_pred         = (const float*)d_in[8];
    const float* b_pred         = (const float*)d_in[9];
    float* out = (float*)d_out;

    // workspace: ESP(f16) | EIP(f16) | ECS(fp8) | ECI(fp8) | WH(f16)
    _Float16* ESP = (_Float16*)d_ws;
    _Float16* EIP = ESP + (size_t)NSTU * CNUM;
    unsigned char* ECS8 = (unsigned char*)(EIP + (size_t)NITEM * CNUM);
    unsigned char* ECI8 = ECS8 + (size_t)NCONC * CNUM;
    _Float16* WH = (_Float16*)(ECI8 + (size_t)NCONC * CNUM);

    proj_mfma<<<PROJ_BLKS, 256, 0, stream>>>(
        stu_fusion, item_fusion, concept_fusion, W_stu, W_item, w_pred,
        ESP, EIP, ECS8, ECI8, WH);

    edge_kernel<<<EDGES / 16, 256, 0, stream>>>(
        stu_idx, item_idx, (const int4*)conc_idx,
        ESP, EIP, ECS8, ECI8, WH, b_pred, out);
}

// Round 4
// 135.830 us; speedup vs baseline: 1.0331x; 1.0331x over previous
//
#include <hip/hip_runtime.h>
#include <hip/hip_bf16.h>
#include <hip/hip_fp16.h>

// Tables: ESP/EIP/ECS/ECI = exp(-logit) in FP16 (R5 reverted fp8: edge is
// VALU-issue bound — VALUBusy 81%, HBM 13.8%, conc tables L2-resident —
// so decode instructions cost, byte savings don't).
// Edge per channel: sigma(a)-sigma(b) = (B-A)/(A*B) with A=1+es*cs, B=1+ei*ci
// computed directly via v_pk_fma (t,u never materialized): 20 pk instr/k.
// No 0.25 pre-scaling (unscaled dn=A*B<=65504 until ~12-sigma joint tail).
// Fraction pair-tree 8->4->2->1 in F32 (v_fma_mix) -> 1 rcp per lane*k.
// 32-bit gather addressing (idx<<7 | li*8), ECS/ECI share one offset.
// DPP butterfly reduction — no LDS pipe.
// Timed-region model (R3 counters): 2x 256MiB harness poison fills ~90us
// structural; controllable = edge ~46us (VALU-bound) + proj ~2us.
constexpr int EDGES = 250000;
constexpr int EMB   = 64;
constexpr int CNUM  = 128;
constexpr int NSTU  = 10000;
constexpr int NITEM = 50000;
constexpr int NCONC = 2048;

constexpr float NEG_LOG2E = -1.44269504088896340736f;

// proj job space: one wave per 16-row strip (conc strips: one wave per table)
constexpr int STU_JOBS  = NSTU  / 16;            // 625
constexpr int ITEM_JOBS = NITEM / 16;            // 3125
constexpr int CONC_JOBS = (NCONC / 16) * 2;      // 256
constexpr int NJOBS     = STU_JOBS + ITEM_JOBS + CONC_JOBS;  // 4006
constexpr int PROJ_BLKS = (NJOBS + 3) / 4;

typedef _Float16 h8 __attribute__((ext_vector_type(8)));
typedef _Float16 h4 __attribute__((ext_vector_type(4)));
typedef _Float16 h2 __attribute__((ext_vector_type(2)));
typedef float    f32x4 __attribute__((ext_vector_type(4)));

__device__ __forceinline__ h2 cvt2(float a, float b) {
#if __has_builtin(__builtin_amdgcn_cvt_pkrtz)
    return __builtin_bit_cast(h2, __builtin_amdgcn_cvt_pkrtz(a, b));
#else
    h2 r; r[0] = (_Float16)a; r[1] = (_Float16)b; return r;
#endif
}

__device__ __forceinline__ h8 pack8(float4 lo, float4 hi) {
    const h2 a = cvt2(lo.x, lo.y);
    const h2 b = cvt2(lo.z, lo.w);
    const h2 c = cvt2(hi.x, hi.y);
    const h2 d = cvt2(hi.z, hi.w);
    const h4 ab = __builtin_shufflevector(a, b, 0, 1, 2, 3);
    const h4 cd = __builtin_shufflevector(c, d, 0, 1, 2, 3);
    return __builtin_shufflevector(ab, cd, 0, 1, 2, 3, 4, 5, 6, 7);
}

// x += dpp-permuted x (full-rate VALU, no LDS pipe)
template <int CTRL>
__device__ __forceinline__ float dppadd(float x) {
    return x + __int_as_float(__builtin_amdgcn_update_dpp(
        0, __float_as_int(x), CTRL, 0xf, 0xf, true));
}

// ---- projection via MFMA: O[r,c] = exp(-dot(F[r,:], W[c, wcol:wcol+64])) ---
__global__ __launch_bounds__(256) void proj_mfma(
        const float* __restrict__ stuF, const float* __restrict__ itemF,
        const float* __restrict__ concF,
        const float* __restrict__ W_stu, const float* __restrict__ W_item,
        const float* __restrict__ w_pred,
        _Float16* __restrict__ ESP, _Float16* __restrict__ EIP,
        _Float16* __restrict__ ECS, _Float16* __restrict__ ECI,
        _Float16* __restrict__ WH) {
    const int tid  = threadIdx.x;
    const int lane = tid & 63;
    const int job  = blockIdx.x * 4 + (tid >> 6);
    if (job >= NJOBS) return;

    if (job == 0) {  // one wave converts w_pred (128 f32) to fp16 once
        const float2 wv2 = ((const float2*)w_pred)[lane];
        h2 wh; wh[0] = (_Float16)wv2.x; wh[1] = (_Float16)wv2.y;
        *(h2*)(WH + 2 * lane) = wh;
    }

    const float* F; const float* W; _Float16* O; int strip, wcol;
    if (job < STU_JOBS) {
        F = stuF;  W = W_stu;  O = ESP; strip = job; wcol = 0;
    } else if (job < STU_JOBS + ITEM_JOBS) {
        F = itemF; W = W_item; O = EIP; strip = job - STU_JOBS; wcol = 0;
    } else {
        const int g = job - STU_JOBS - ITEM_JOBS;
        F = concF; W = (g & 1) ? W_item : W_stu; O = (g & 1) ? ECI : ECS;
        strip = g >> 1; wcol = EMB;
    }

    const int m = lane & 15;       // A row / B channel / D col
    const int q = lane >> 4;       // quad
    const int row = strip * 16 + m;

    const float4* fa = (const float4*)(F + (size_t)row * EMB + q * 8);
    const float4* fb = (const float4*)(F + (size_t)row * EMB + 32 + q * 8);
    const h8 A0 = pack8(fa[0], fa[1]);
    const h8 A1 = pack8(fb[0], fb[1]);

    const int orow = strip * 16 + q * 4;

#pragma unroll
    for (int ct = 0; ct < 8; ++ct) {
        const int ch = ct * 16 + m;
        const float* wr = W + (size_t)ch * (2 * EMB) + wcol;
        const float4* wb0 = (const float4*)(wr + q * 8);
        const float4* wb1 = (const float4*)(wr + 32 + q * 8);
        const h8 B0 = pack8(wb0[0], wb0[1]);
        const h8 B1 = pack8(wb1[0], wb1[1]);

        f32x4 acc = {0.f, 0.f, 0.f, 0.f};
        acc = __builtin_amdgcn_mfma_f32_16x16x32_f16(A0, B0, acc, 0, 0, 0);
        acc = __builtin_amdgcn_mfma_f32_16x16x32_f16(A1, B1, acc, 0, 0, 0);

#pragma unroll
        for (int r = 0; r < 4; ++r) {
            const float e = __builtin_amdgcn_exp2f(acc[r] * NEG_LOG2E);
            O[(unsigned)(orow + r) * CNUM + ct * 16 + m] = (_Float16)e;
        }
    }
}

__device__ __forceinline__ float sigm(float x) {
    return __builtin_amdgcn_rcpf(1.f + __builtin_amdgcn_exp2f(x * NEG_LOG2E));
}

// ---- edge phase: 4 edges/wave, 16 lanes/edge, lane owns 8 channels --------
__global__ __launch_bounds__(256) void edge_kernel(
        const int*  __restrict__ stu_idx,
        const int*  __restrict__ item_idx,
        const int4* __restrict__ conc_idx,
        const _Float16* __restrict__ ESP,
        const _Float16* __restrict__ EIP,
        const _Float16* __restrict__ ECS,
        const _Float16* __restrict__ ECI,
        const _Float16* __restrict__ WH,
        const float* __restrict__ b_pred,
        float* __restrict__ out) {
    const int lane = threadIdx.x & 63;
    const int wvg  = (blockIdx.x * blockDim.x + threadIdx.x) >> 6;
    const int sub  = lane >> 4;      // edge within wave 0..3
    const int li   = lane & 15;      // lane within edge; owns ch li*8..li*8+7
    const int e    = wvg * 4 + sub;  // grid sized exactly
    const unsigned co = (unsigned)(li * 8);

    const int s  = stu_idx[e];
    const int it = item_idx[e];
    const int4 c4 = conc_idx[e];

    // 32-bit offsets: idx*128 + li*8 (fits well under 2^32); SGPR base +
    // VGPR voffset addressing, no 64-bit VALU math.
    const h8 es = *(const h8*)(ESP + (((unsigned)s  << 7) + co));
    const h8 ei = *(const h8*)(EIP + (((unsigned)it << 7) + co));
    const h8 w8 = *(const h8*)(WH + co);
    const float b = b_pred[0];

    const _Float16 O1 = (_Float16)1.f;
    const h8 ONE = {O1, O1, O1, O1, O1, O1, O1, O1};

    const int ck[4] = {c4.x, c4.y, c4.z, c4.w};
    float p[4];
#pragma unroll
    for (int k = 0; k < 4; ++k) {
        const unsigned off = ((unsigned)ck[k] << 7) + co;
        const h8 cs = *(const h8*)(ECS + off);
        const h8 ci = *(const h8*)(ECI + off);
        const h8 Aq = es * cs + ONE;       // 1+t        (v_pk_fma)
        const h8 Bq = ei * ci + ONE;       // 1+u        (v_pk_fma)
        const h8 dn = Aq * Bq;             // den, <=65504 till ~12-sigma
        const h8 nm = w8 * (Bq - Aq);      // w*(u-t)
        // pair-tree in F32 (v_fma_mix reads fp16 ops directly): 8->4->2->1
        float N1[4], D1[4];
#pragma unroll
        for (int i = 0; i < 4; ++i) {
            N1[i] = (float)nm[i] * (float)dn[i + 4]
                  + (float)nm[i + 4] * (float)dn[i];
            D1[i] = (float)dn[i] * (float)dn[i + 4];
        }
        const float N2a = N1[0] * D1[2] + N1[2] * D1[0];
        const float N2b = N1[1] * D1[3] + N1[3] * D1[1];
        const float D2a = D1[0] * D1[2];
        const float D2b = D1[1] * D1[3];
        const float N3 = N2a * D2b + N2b * D2a;
        const float D3 = D2a * D2b;        // prod of 8 dens; f32-safe
        // single rcp per (lane,k)
        p[k] = N3 * __builtin_amdgcn_rcpf(D3);
    }

    // 16-lane sum via DPP butterfly; xor-basis {1,2,7,15} spans the group.
#pragma unroll
    for (int j = 0; j < 4; ++j) p[j] = dppadd<0xB1>(p[j]);   // quad_perm xor1
#pragma unroll
    for (int j = 0; j < 4; ++j) p[j] = dppadd<0x4E>(p[j]);   // quad_perm xor2
#pragma unroll
    for (int j = 0; j < 4; ++j) p[j] = dppadd<0x141>(p[j]);  // row_half_mirror
#pragma unroll
    for (int j = 0; j < 4; ++j) p[j] = dppadd<0x140>(p[j]);  // row_mirror

    const float r = 0.25f * (sigm(p[0] + b) + sigm(p[1] + b) +
                             sigm(p[2] + b) + sigm(p[3] + b));
    if (li == 0) out[e] = r;
}

extern "C" void kernel_launch(void* const* d_in, const int* in_sizes, int n_in,
                              void* d_out, int out_size, void* d_ws, size_t ws_size,
                              hipStream_t stream) {
    const int* stu_idx  = (const int*)d_in[0];
    const int* item_idx = (const int*)d_in[1];
    const int* conc_idx = (const int*)d_in[2];
    const float* stu_fusion     = (const float*)d_in[3];
    const float* item_fusion    = (const float*)d_in[4];
    const float* concept_fusion = (const float*)d_in[5];
    const float* W_stu          = (const float*)d_in[6];
    const float* W_item         = (const float*)d_in[7];
    const float* w_pred         = (const float*)d_in[8];
    const float* b_pred         = (const float*)d_in[9];
    float* out = (float*)d_out;

    // workspace (_Float16): ESP | EIP | ECS | ECI | WH
    _Float16* ESP = (_Float16*)d_ws;
    _Float16* EIP = ESP + (size_t)NSTU * CNUM;
    _Float16* ECS = EIP + (size_t)NITEM * CNUM;
    _Float16* ECI = ECS + (size_t)NCONC * CNUM;
    _Float16* WH  = ECI + (size_t)NCONC * CNUM;

    proj_mfma<<<PROJ_BLKS, 256, 0, stream>>>(
        stu_fusion, item_fusion, concept_fusion, W_stu, W_item, w_pred,
        ESP, EIP, ECS, ECI, WH);

    edge_kernel<<<EDGES / 16, 256, 0, stream>>>(
        stu_idx, item_idx, (const int4*)conc_idx,
        ESP, EIP, ECS, ECI, WH, b_pred, out);
}